// Round 3
// baseline (3353.107 us; speedup 1.0000x reference)
//
#include <hip/hip_runtime.h>
#include <math.h>

#define BN 2
#define HH 128
#define WW 160
#define HWn (HH*WW)          // 20480
#define CD 128
#define TT (BN*HWn)          // 40960 tokens per stream
#define TOKN ((size_t)TT*CD) // 5,242,880 floats

// ---------------- block reduce (128 threads = 2 waves) ----------------
__device__ __forceinline__ float block_reduce_sum_128(float v, float* red){
#pragma unroll
  for (int o = 32; o > 0; o >>= 1) v += __shfl_xor(v, o, 64);
  int lane = threadIdx.x & 63, wid = threadIdx.x >> 6;
  if (lane == 0) red[wid] = v;
  __syncthreads();
  float r = red[0] + red[1];
  __syncthreads();
  return r;
}

// ---------------- K0: tiny precompute: proj mats + SE gate ----------------
__global__ void k_small(const float* __restrict__ ref_proj, const float* __restrict__ src_i2w,
                        const float* __restrict__ cam16,
                        const float* __restrict__ bn1_g, const float* __restrict__ bn1_b,
                        const float* __restrict__ fc1_w, const float* __restrict__ fc1_b,
                        const float* __restrict__ fc2_w, const float* __restrict__ fc2_b,
                        const float* __restrict__ ser_w, const float* __restrict__ ser_b,
                        const float* __restrict__ see_w, const float* __restrict__ see_b,
                        float* __restrict__ projsmall, float* __restrict__ gate){
  __shared__ float mi[BN][16], t1[BN][128], t2[BN][128];
  int tid = threadIdx.x;
  const float inv_std = rsqrtf(1.0f + 1e-5f);
  if (tid < 32){
    int b = tid >> 4, idx = tid & 15, i = idx >> 2, k = idx & 3;
    float acc = 0.f;
    for (int j = 0; j < 4; j++) acc += ref_proj[b*16 + i*4 + j] * src_i2w[b*16 + j*4 + k];
    if (i < 3 && k < 3) projsmall[b*12 + i*3 + k] = acc;
    if (i < 3 && k == 3) projsmall[b*12 + 9 + i] = acc;
    mi[b][idx] = cam16[b*16 + idx] * inv_std * bn1_g[idx] + bn1_b[idx];
  }
  __syncthreads();
  int b = tid >> 7, c = tid & 127;
  float a = 0.f;
  for (int j = 0; j < 16; j++) a += mi[b][j] * fc1_w[j*128 + c];
  t1[b][c] = fmaxf(a + fc1_b[c], 0.f);
  __syncthreads();
  a = 0.f;
  for (int k = 0; k < 128; k++) a += t1[b][k] * fc2_w[k*128 + c];
  t2[b][c] = a + fc2_b[c];
  __syncthreads();
  a = 0.f;
  for (int k = 0; k < 128; k++) a += t2[b][k] * ser_w[k*128 + c];
  t1[b][c] = fmaxf(a + ser_b[c], 0.f);
  __syncthreads();
  a = 0.f;
  for (int k = 0; k < 128; k++) a += t1[b][k] * see_w[k*128 + c];
  a += see_b[c];
  gate[b*128 + c] = 1.f / (1.f + expf(-a));
}

// ---------------- K1: conv3x3(depth) + bn + relu + gate, pixel-major ----------------
__global__ __launch_bounds__(128) void k_hmap(const float* __restrict__ depth,
                       const float* __restrict__ rc_w, const float* __restrict__ rc_b,
                       const float* __restrict__ bn2_g, const float* __restrict__ bn2_b,
                       const float* __restrict__ gate, float* __restrict__ G){
  int bi = blockIdx.x; int n = bi / HWn; int p = bi - n*HWn;
  int y = p / WW, x = p - y*WW;
  int c = threadIdx.x;
  const float inv_std = rsqrtf(1.f + 1e-5f);
  float acc = 0.f;
#pragma unroll
  for (int ky = 0; ky < 3; ky++){
    int yy = y + ky - 1;
#pragma unroll
    for (int kx = 0; kx < 3; kx++){
      int xx = x + kx - 1;
      float v = (yy >= 0 && yy < HH && xx >= 0 && xx < WW) ? depth[n*HWn + yy*WW + xx] : 0.f;
      acc += v * rc_w[c*9 + ky*3 + kx];
    }
  }
  acc += rc_b[c];
  acc = fmaxf(acc * inv_std * bn2_g[c] + bn2_b[c], 0.f);
  G[(size_t)bi*128 + c] = acc * gate[n*128 + c];
}

// ---------------- generic f32 GEMM: C[T,N] = act(A[T,K] @ W[K,N] + bias (+resid)) ----------------
template<int ACT>  // 0 none, 1 relu, 2 elu+1
__global__ __launch_bounds__(256) void k_gemm(const float* __restrict__ A, const float* __restrict__ Wm,
       const float* __restrict__ bias, const float* __restrict__ resid,
       float* __restrict__ C, int K, int ldW, int ldC){
  __shared__ float Wt[64][128];
  __shared__ float At[64][33];
  int tid = threadIdx.x;
  int tx = tid & 31, ty = tid >> 5;
  int t0 = blockIdx.x * 32;
  int oc0 = blockIdx.y * 128;
  float acc[4][4] = {};
  for (int kb = 0; kb < K; kb += 64){
#pragma unroll
    for (int r = 0; r < 8; r++){
      int e = (r*256 + tid)*4;
      int kk = e >> 7, oo = e & 127;
      *(float4*)&Wt[kk][oo] = *(const float4*)&Wm[(size_t)(kb+kk)*ldW + oc0 + oo];
    }
    {
      int t = tid >> 3, seg = tid & 7;
      const float* ap = &A[(size_t)(t0+t)*K + kb + seg*8];
      float4 v0 = *(const float4*)ap;
      float4 v1 = *(const float4*)(ap+4);
      int k = seg*8;
      At[k+0][t]=v0.x; At[k+1][t]=v0.y; At[k+2][t]=v0.z; At[k+3][t]=v0.w;
      At[k+4][t]=v1.x; At[k+5][t]=v1.y; At[k+6][t]=v1.z; At[k+7][t]=v1.w;
    }
    __syncthreads();
#pragma unroll 4
    for (int k = 0; k < 64; k++){
      float4 w = *(float4*)&Wt[k][tx*4];
      float av[4];
#pragma unroll
      for (int i = 0; i < 4; i++) av[i] = At[k][ty*4 + i];
#pragma unroll
      for (int i = 0; i < 4; i++){
        acc[i][0] += av[i]*w.x; acc[i][1] += av[i]*w.y;
        acc[i][2] += av[i]*w.z; acc[i][3] += av[i]*w.w;
      }
    }
    __syncthreads();
  }
#pragma unroll
  for (int i = 0; i < 4; i++){
    int t = t0 + ty*4 + i;
#pragma unroll
    for (int j = 0; j < 4; j++){
      int o = tx*4 + j;
      float v = acc[i][j] + bias[oc0 + o];
      if (resid) v += resid[(size_t)t*128 + oc0 + o];
      if (ACT == 1) v = fmaxf(v, 0.f);
      if (ACT == 2) v = v > 0.f ? v + 1.f : expf(v);
      C[(size_t)t*ldC + oc0 + o] = v;
    }
  }
}

// ---------------- KV partial: per (n,h,chunk of 256 tokens): 16x16 KV + 16 Ksum ----------------
__global__ __launch_bounds__(256) void k_kvpart(const float* __restrict__ Kb, const float* __restrict__ Vb,
                         float* __restrict__ part){
  __shared__ float Ks[256][16], Vs[256][16];
  int bi = blockIdx.x;
  int chunk = bi % 80; int h = (bi / 80) & 7; int n = bi / 640;
  int s0 = chunk * 256;
  int tid = threadIdx.x;
#pragma unroll
  for (int r = 0; r < 16; r++){
    int idx = r*256 + tid;
    int s = idx >> 4, d = idx & 15;
    size_t g = ((size_t)(n*HWn + s0 + s))*128 + h*16 + d;
    Ks[s][d] = Kb[g];
    Vs[s][d] = Vb[g];
  }
  __syncthreads();
  int m = tid >> 4, d = tid & 15;
  float acc = 0.f;
  for (int s = 0; s < 256; s++) acc += Ks[s][d] * Vs[s][m];
  part[(size_t)bi*272 + tid] = acc;
  if (m == 0){
    float ks = 0.f;
    for (int s = 0; s < 256; s++) ks += Ks[s][d];
    part[(size_t)bi*272 + 256 + d] = ks;
  }
}

__global__ void k_kvreduce(const float* __restrict__ part, float* __restrict__ fin){
  int nh = blockIdx.x;
  int o = threadIdx.x;
  if (o < 272){
    float acc = 0.f;
    for (int c2 = 0; c2 < 80; c2++) acc += part[((size_t)nh*80 + c2)*272 + o];
    fin[nh*272 + o] = acc;
  }
}

// ---------------- attention out + out-proj + residual + LN ----------------
__global__ __launch_bounds__(128) void k_attn(const float* __restrict__ Q, const float* __restrict__ Xin,
      const float* __restrict__ kvfin, const float* __restrict__ W3, const float* __restrict__ b3,
      const float* __restrict__ g0, const float* __restrict__ b0, float* __restrict__ XLN){
  __shared__ float W3s[64][128];
  __shared__ float vs[16][128];
  __shared__ float kvs[8][272];
  __shared__ float qs[128];
  __shared__ float red[2];
  int tid = threadIdx.x;
  int tb = blockIdx.x * 16;
  int n = tb / HWn;
  for (int i = tid; i < 8*272; i += 128) ((float*)kvs)[i] = kvfin[n*2176 + i];
  int h = tid >> 4, m = tid & 15;
  float xacc[16];
  float bb3 = b3[tid];
  for (int i = 0; i < 16; i++){
    size_t row = (size_t)(tb + i)*128;
    qs[tid] = Q[row + tid];
    __syncthreads();
    float den = 0.f, num = 0.f;
#pragma unroll
    for (int d = 0; d < 16; d++){
      float qv = qs[h*16 + d];
      den += qv * kvs[h][256 + d];
      num += qv * kvs[h][m*16 + d];
    }
    vs[i][tid] = num / (den + 1e-6f);
    xacc[i] = Xin[row + tid] + bb3;
    __syncthreads();
  }
  for (int kb = 0; kb < 128; kb += 64){
    __syncthreads();
    for (int idx = tid; idx < 64*128; idx += 128)
      W3s[idx >> 7][idx & 127] = W3[(size_t)(kb + (idx >> 7))*128 + (idx & 127)];
    __syncthreads();
    for (int i = 0; i < 16; i++){
      float a = xacc[i];
#pragma unroll 8
      for (int k = 0; k < 64; k++) a += vs[i][kb + k] * W3s[k][tid];
      xacc[i] = a;
    }
  }
  float g = g0[tid], bl = b0[tid];
  for (int i = 0; i < 16; i++){
    float v = xacc[i];
    float mean = block_reduce_sum_128(v, red) * (1.f/128.f);
    float dv = v - mean;
    float var = block_reduce_sum_128(dv*dv, red) * (1.f/128.f);
    XLN[(size_t)(tb + i)*128 + tid] = dv * rsqrtf(var + 1e-5f) * g + bl;
  }
}

// ---------------- in-place LN ----------------
__global__ __launch_bounds__(128) void k_ln(float* __restrict__ Cm, const float* __restrict__ g1, const float* __restrict__ b1){
  __shared__ float red[2];
  int tid = threadIdx.x; int tb = blockIdx.x * 16;
  float g = g1[tid], bl = b1[tid];
  for (int i = 0; i < 16; i++){
    size_t row = (size_t)(tb + i)*128;
    float v = Cm[row + tid];
    float mean = block_reduce_sum_128(v, red) * (1.f/128.f);
    float dv = v - mean;
    float var = block_reduce_sum_128(dv*dv, red) * (1.f/128.f);
    Cm[row + tid] = dv * rsqrtf(var + 1e-5f) * g + bl;
  }
}

// ---------------- homography warp + bilinear sample (pixel-major ctx) ----------------
__global__ __launch_bounds__(128) void k_warp(const float* __restrict__ ctxref, const float* __restrict__ depth,
     const float* __restrict__ projs, float* __restrict__ ctxsrc){
  int bi = blockIdx.x; int n = bi / HWn; int p = bi - n*HWn;
  int y = p / WW, x = p - y*WW;
  const float* pr = &projs[n*12];
  float d = depth[n*HWn + p];
  float fx = (float)x, fy = (float)y;
  float px = (pr[0]*fx + pr[1]*fy + pr[2])*d + pr[9];
  float py = (pr[3]*fx + pr[4]*fy + pr[5])*d + pr[10];
  float pz = (pr[6]*fx + pr[7]*fy + pr[8])*d + pr[11];
  if (pz == 0.f) pz = 1e-9f;
  float xs = px/pz, ys = py/pz;
  float x0 = floorf(xs), y0 = floorf(ys);
  float wx = xs - x0, wy = ys - y0;
  int c = threadIdx.x;
  float acc = 0.f;
#pragma unroll
  for (int dy = 0; dy < 2; dy++){
    float cy = y0 + dy;
    float wyv = dy ? wy : 1.f - wy;
#pragma unroll
    for (int dx = 0; dx < 2; dx++){
      float cx = x0 + dx;
      float wxv = dx ? wx : 1.f - wx;
      bool valid = (cx >= 0.f) && (cx <= (float)(WW-1)) && (cy >= 0.f) && (cy <= (float)(HH-1));
      int xi = (int)fminf(fmaxf(cx, 0.f), (float)(WW-1));
      int yi = (int)fminf(fmaxf(cy, 0.f), (float)(HH-1));
      float v = ctxref[((size_t)(n*HWn) + yi*WW + xi)*128 + c];
      acc += valid ? wxv*wyv*v : 0.f;
    }
  }
  ctxsrc[(size_t)bi*128 + c] = acc;
}

// ---------------- token build: transpose feature + PE + ctx ----------------
__global__ __launch_bounds__(256) void k_build(const float* __restrict__ feat, const float* __restrict__ ctx,
      float* __restrict__ out){
  __shared__ float tile[32][33];
  int tx = threadIdx.x, ty = threadIdx.y;
  int p0 = blockIdx.x*32, c0 = blockIdx.y*32, b = blockIdx.z;
  for (int i = ty; i < 32; i += 8)
    tile[i][tx] = feat[((size_t)(b*CD + c0 + i))*HWn + p0 + tx];
  __syncthreads();
  const float LOG1E4_32 = 0.28782313662425572f;  // ln(10000)/32
  for (int r = ty; r < 32; r += 8){
    int p = p0 + r, c = c0 + tx;
    int y = p / WW, x = p - y*WW;
    int i = c >> 2, j = c & 3;
    float dv = expf(-(float)i * LOG1E4_32);
    float pos = (j < 2) ? (float)(x + 1) : (float)(y + 1);
    float arg = pos * dv;
    float pe = (j & 1) ? cosf(arg) : sinf(arg);
    size_t o = ((size_t)(b*HWn) + p)*128 + c;
    out[o] = tile[tx][r] + pe + ctx[o];
  }
}

// ---------------- host ----------------
extern "C" void kernel_launch(void* const* d_in, const int* in_sizes, int n_in,
                              void* d_out, int out_size, void* d_ws, size_t ws_size,
                              hipStream_t stream) {
  const float* ref_feature = (const float*)d_in[0];
  const float* src_feature = (const float*)d_in[1];
  const float* ref_proj    = (const float*)d_in[2];
  const float* ref_i2w     = (const float*)d_in[4];
  const float* src_i2w     = (const float*)d_in[5];
  const float* depth       = (const float*)d_in[6];
  const float* attn_w      = (const float*)d_in[7];
  const float* attn_b      = (const float*)d_in[8];
  const float* ffn_w1      = (const float*)d_in[9];
  const float* ffn_b1      = (const float*)d_in[10];
  const float* ffn_w2      = (const float*)d_in[11];
  const float* ffn_b2      = (const float*)d_in[12];
  const float* ln_g        = (const float*)d_in[13];
  const float* ln_b        = (const float*)d_in[14];
  const float* rc_w        = (const float*)d_in[15];
  const float* rc_b        = (const float*)d_in[16];
  const float* bn2_g       = (const float*)d_in[17];
  const float* bn2_b       = (const float*)d_in[18];
  const float* cc_w        = (const float*)d_in[19];
  const float* cc_b        = (const float*)d_in[20];
  const float* bn1_g       = (const float*)d_in[21];
  const float* bn1_b       = (const float*)d_in[22];
  const float* fc1_w       = (const float*)d_in[23];
  const float* fc1_b       = (const float*)d_in[24];
  const float* fc2_w       = (const float*)d_in[25];
  const float* fc2_b       = (const float*)d_in[26];
  const float* ser_w       = (const float*)d_in[27];
  const float* ser_b       = (const float*)d_in[28];
  const float* see_w       = (const float*)d_in[29];
  const float* see_b       = (const float*)d_in[30];

  // ws layout: 3 token buffers + small partials (~64.3 MB total)
  float* ws = (float*)d_ws;
  float* QB = ws;                   // TOKN (also hmap out, XLN)
  float* KB = QB + TOKN;            // TOKN (also ref_ctx; FFN hidden spans KB+VB)
  float* VB = KB + TOKN;            // TOKN (also src_ctx)
  float* KVPART = VB + TOKN;        // 1280*272
  float* KVFIN  = KVPART + 1280*272;// 16*272
  float* PROJ   = KVFIN + 16*272;   // 24 (pad 32)
  float* GATE   = PROJ + 32;        // 256
  // ref/src token streams live in d_out for the whole network
  float* Rm = (float*)d_out;        // TOKN
  float* Sm = Rm + TOKN;            // TOKN

  // preamble
  k_small<<<1, 256, 0, stream>>>(ref_proj, src_i2w, ref_i2w, bn1_g, bn1_b, fc1_w, fc1_b,
                                 fc2_w, fc2_b, ser_w, ser_b, see_w, see_b, PROJ, GATE);
  k_hmap<<<TT, 128, 0, stream>>>(depth, rc_w, rc_b, bn2_g, bn2_b, GATE, QB);
  k_gemm<0><<<dim3(TT/32, 1), 256, 0, stream>>>(QB, cc_w, cc_b, nullptr, KB, 128, 128, 128);
  k_warp<<<TT, 128, 0, stream>>>(KB, depth, PROJ, VB);
  k_build<<<dim3(HWn/32, 4, BN), dim3(32, 8), 0, stream>>>(ref_feature, KB, Rm);
  k_build<<<dim3(HWn/32, 4, BN), dim3(32, 8), 0, stream>>>(src_feature, VB, Sm);

  // in-place encoder: x is dead after k_attn (residual read), srcp dead after K/V gemms,
  // so FFN2 may write dst==x. Kernels are stream-serialized.
  auto enc = [&](float* x, const float* srcp, int l){
    const float* W  = attn_w + (size_t)l*4*16384;
    const float* Bv = attn_b + (size_t)l*4*128;
    k_gemm<2><<<dim3(TT/32, 1), 256, 0, stream>>>(x,    W + 0*16384, Bv + 0,   nullptr, QB, 128, 128, 128);
    k_gemm<2><<<dim3(TT/32, 1), 256, 0, stream>>>(srcp, W + 1*16384, Bv + 128, nullptr, KB, 128, 128, 128);
    k_gemm<0><<<dim3(TT/32, 1), 256, 0, stream>>>(srcp, W + 2*16384, Bv + 256, nullptr, VB, 128, 128, 128);
    k_kvpart<<<1280, 256, 0, stream>>>(KB, VB, KVPART);
    k_kvreduce<<<16, 320, 0, stream>>>(KVPART, KVFIN);
    k_attn<<<TT/16, 128, 0, stream>>>(QB, x, KVFIN, W + 3*16384, Bv + 3*128,
                                      ln_g + (size_t)l*256, ln_b + (size_t)l*256, QB);
    k_gemm<1><<<dim3(TT/32, 2), 256, 0, stream>>>(QB, ffn_w1 + (size_t)l*128*256, ffn_b1 + (size_t)l*256,
                                                  nullptr, KB, 128, 256, 256);
    k_gemm<0><<<dim3(TT/32, 1), 256, 0, stream>>>(KB, ffn_w2 + (size_t)l*256*128, ffn_b2 + (size_t)l*128,
                                                  QB, x, 256, 128, 128);
    k_ln<<<TT/16, 128, 0, stream>>>(x, ln_g + (size_t)l*256 + 128, ln_b + (size_t)l*256 + 128);
  };

  // layer 0: self
  enc(Rm, Rm, 0); enc(Sm, Sm, 0);
  // layer 1: cross (src uses updated ref)
  enc(Rm, Sm, 1); enc(Sm, Rm, 1);
  // layer 2: self
  enc(Rm, Rm, 2); enc(Sm, Sm, 2);
  // layer 3: cross, final results land in d_out
  enc(Rm, Sm, 3); enc(Sm, Rm, 3);
}

// Round 5
// 2028.588 us; speedup vs baseline: 1.6529x; 1.6529x over previous
//
#include <hip/hip_runtime.h>
#include <math.h>

#define BN 2
#define HH 128
#define WW 160
#define HWn (HH*WW)          // 20480
#define CD 128
#define TT (BN*HWn)          // 40960 tokens per stream
#define TOKN ((size_t)TT*CD) // 5,242,880 floats

// ---------------- K0: tiny precompute: proj mats + SE gate ----------------
__global__ void k_small(const float* __restrict__ ref_proj, const float* __restrict__ src_i2w,
                        const float* __restrict__ cam16,
                        const float* __restrict__ bn1_g, const float* __restrict__ bn1_b,
                        const float* __restrict__ fc1_w, const float* __restrict__ fc1_b,
                        const float* __restrict__ fc2_w, const float* __restrict__ fc2_b,
                        const float* __restrict__ ser_w, const float* __restrict__ ser_b,
                        const float* __restrict__ see_w, const float* __restrict__ see_b,
                        float* __restrict__ projsmall, float* __restrict__ gate){
  __shared__ float mi[BN][16], t1[BN][128], t2[BN][128];
  int tid = threadIdx.x;
  const float inv_std = rsqrtf(1.0f + 1e-5f);
  if (tid < 32){
    int b = tid >> 4, idx = tid & 15, i = idx >> 2, k = idx & 3;
    float acc = 0.f;
    for (int j = 0; j < 4; j++) acc += ref_proj[b*16 + i*4 + j] * src_i2w[b*16 + j*4 + k];
    if (i < 3 && k < 3) projsmall[b*12 + i*3 + k] = acc;
    if (i < 3 && k == 3) projsmall[b*12 + 9 + i] = acc;
    mi[b][idx] = cam16[b*16 + idx] * inv_std * bn1_g[idx] + bn1_b[idx];
  }
  __syncthreads();
  int b = tid >> 7, c = tid & 127;
  float a = 0.f;
  for (int j = 0; j < 16; j++) a += mi[b][j] * fc1_w[j*128 + c];
  t1[b][c] = fmaxf(a + fc1_b[c], 0.f);
  __syncthreads();
  a = 0.f;
  for (int k = 0; k < 128; k++) a += t1[b][k] * fc2_w[k*128 + c];
  t2[b][c] = a + fc2_b[c];
  __syncthreads();
  a = 0.f;
  for (int k = 0; k < 128; k++) a += t2[b][k] * ser_w[k*128 + c];
  t1[b][c] = fmaxf(a + ser_b[c], 0.f);
  __syncthreads();
  a = 0.f;
  for (int k = 0; k < 128; k++) a += t1[b][k] * see_w[k*128 + c];
  a += see_b[c];
  gate[b*128 + c] = 1.f / (1.f + expf(-a));
}

// ---------------- K1: conv3x3(depth) + bn + relu + gate, pixel-major ----------------
__global__ __launch_bounds__(128) void k_hmap(const float* __restrict__ depth,
                       const float* __restrict__ rc_w, const float* __restrict__ rc_b,
                       const float* __restrict__ bn2_g, const float* __restrict__ bn2_b,
                       const float* __restrict__ gate, float* __restrict__ G){
  int bi = blockIdx.x; int n = bi / HWn; int p = bi - n*HWn;
  int y = p / WW, x = p - y*WW;
  int c = threadIdx.x;
  const float inv_std = rsqrtf(1.f + 1e-5f);
  float acc = 0.f;
#pragma unroll
  for (int ky = 0; ky < 3; ky++){
    int yy = y + ky - 1;
#pragma unroll
    for (int kx = 0; kx < 3; kx++){
      int xx = x + kx - 1;
      float v = (yy >= 0 && yy < HH && xx >= 0 && xx < WW) ? depth[n*HWn + yy*WW + xx] : 0.f;
      acc += v * rc_w[c*9 + ky*3 + kx];
    }
  }
  acc += rc_b[c];
  acc = fmaxf(acc * inv_std * bn2_g[c] + bn2_b[c], 0.f);
  G[(size_t)bi*128 + c] = acc * gate[n*128 + c];
}

// ---- generic f32 GEMM: C[T,N] = [LN](act(A[T,K] @ W[K,N] + bias (+resid))) ----
// When LN==1: N must be 128 (grid.y==1); LayerNorm applied per token row.
template<int ACT, int LN>  // ACT: 0 none, 1 relu, 2 elu+1
__global__ __launch_bounds__(256) void k_gemm(const float* __restrict__ A, const float* __restrict__ Wm,
       const float* __restrict__ bias, const float* __restrict__ resid,
       float* __restrict__ C, int K, int ldW, int ldC,
       const float* __restrict__ lng, const float* __restrict__ lnb){
  __shared__ float Wt[64][128];
  __shared__ float At[64][33];
  int tid = threadIdx.x;
  int tx = tid & 31, ty = tid >> 5;
  int t0 = blockIdx.x * 32;
  int oc0 = blockIdx.y * 128;
  float acc[4][4] = {};
  for (int kb = 0; kb < K; kb += 64){
#pragma unroll
    for (int r = 0; r < 8; r++){
      int e = (r*256 + tid)*4;
      int kk = e >> 7, oo = e & 127;
      *(float4*)&Wt[kk][oo] = *(const float4*)&Wm[(size_t)(kb+kk)*ldW + oc0 + oo];
    }
    {
      int t = tid >> 3, seg = tid & 7;
      const float* ap = &A[(size_t)(t0+t)*K + kb + seg*8];
      float4 v0 = *(const float4*)ap;
      float4 v1 = *(const float4*)(ap+4);
      int k = seg*8;
      At[k+0][t]=v0.x; At[k+1][t]=v0.y; At[k+2][t]=v0.z; At[k+3][t]=v0.w;
      At[k+4][t]=v1.x; At[k+5][t]=v1.y; At[k+6][t]=v1.z; At[k+7][t]=v1.w;
    }
    __syncthreads();
#pragma unroll 4
    for (int k = 0; k < 64; k++){
      float4 w = *(float4*)&Wt[k][tx*4];
      float av[4];
#pragma unroll
      for (int i = 0; i < 4; i++) av[i] = At[k][ty*4 + i];
#pragma unroll
      for (int i = 0; i < 4; i++){
        acc[i][0] += av[i]*w.x; acc[i][1] += av[i]*w.y;
        acc[i][2] += av[i]*w.z; acc[i][3] += av[i]*w.w;
      }
    }
    __syncthreads();
  }
  float4 g4, b4;
  if (LN){ g4 = *(const float4*)&lng[tx*4]; b4 = *(const float4*)&lnb[tx*4]; }
#pragma unroll
  for (int i = 0; i < 4; i++){
    int t = t0 + ty*4 + i;
    float v[4];
#pragma unroll
    for (int j = 0; j < 4; j++){
      int o = tx*4 + j;
      float x = acc[i][j] + bias[oc0 + o];
      if (resid) x += resid[(size_t)t*128 + oc0 + o];
      if (ACT == 1) x = fmaxf(x, 0.f);
      if (ACT == 2) x = x > 0.f ? x + 1.f : expf(x);
      v[j] = x;
    }
    if (LN){
      // row t is held by the 32 lanes sharing ty (contiguous half-wave).
      float s = v[0]+v[1]+v[2]+v[3];
#pragma unroll
      for (int o2 = 16; o2 >= 1; o2 >>= 1) s += __shfl_xor(s, o2);
      float mean = s * (1.f/128.f);
      float q = 0.f;
#pragma unroll
      for (int j = 0; j < 4; j++){ float d = v[j]-mean; q += d*d; }
#pragma unroll
      for (int o2 = 16; o2 >= 1; o2 >>= 1) q += __shfl_xor(q, o2);
      float rstd = rsqrtf(q*(1.f/128.f) + 1e-5f);
      v[0] = (v[0]-mean)*rstd*g4.x + b4.x;
      v[1] = (v[1]-mean)*rstd*g4.y + b4.y;
      v[2] = (v[2]-mean)*rstd*g4.z + b4.z;
      v[3] = (v[3]-mean)*rstd*g4.w + b4.w;
    }
#pragma unroll
    for (int j = 0; j < 4; j++)
      C[(size_t)t*ldC + oc0 + tx*4 + j] = v[j];
  }
}

// ---------------- KV partial: per (n,h,chunk of 256 tokens): 16x16 KV + 16 Ksum ----------------
__global__ __launch_bounds__(256) void k_kvpart(const float* __restrict__ Kb, const float* __restrict__ Vb,
                         float* __restrict__ part){
  __shared__ float Ks[256][16], Vs[256][16];
  int bi = blockIdx.x;
  int chunk = bi % 80; int h = (bi / 80) & 7; int n = bi / 640;
  int s0 = chunk * 256;
  int tid = threadIdx.x;
#pragma unroll
  for (int r = 0; r < 16; r++){
    int idx = r*256 + tid;
    int s = idx >> 4, d = idx & 15;
    size_t g = ((size_t)(n*HWn + s0 + s))*128 + h*16 + d;
    Ks[s][d] = Kb[g];
    Vs[s][d] = Vb[g];
  }
  __syncthreads();
  int m = tid >> 4, d = tid & 15;
  float acc = 0.f;
  for (int s = 0; s < 256; s++) acc += Ks[s][d] * Vs[s][m];
  part[(size_t)bi*272 + tid] = acc;
  if (m == 0){
    float ks = 0.f;
    for (int s = 0; s < 256; s++) ks += Ks[s][d];
    part[(size_t)bi*272 + 256 + d] = ks;
  }
}

__global__ void k_kvreduce(const float* __restrict__ part, float* __restrict__ fin){
  int nh = blockIdx.x;
  int o = threadIdx.x;
  if (o < 272){
    float acc = 0.f;
    for (int c2 = 0; c2 < 80; c2++) acc += part[((size_t)nh*80 + c2)*272 + o];
    fin[nh*272 + o] = acc;
  }
}

// ---------------- attention V: V[t,c] = Q[t,h,:]·KV[h,m,:] / (Q[t,h,:]·Ksum[h,:]+eps) ----------------
__global__ __launch_bounds__(256) void k_attnv(const float* __restrict__ Q,
      const float* __restrict__ kvfin, float* __restrict__ Vout){
  __shared__ float kvs[2176];       // 8 heads x 272
  __shared__ float qs[32][128];
  int tb = blockIdx.x * 32;
  int n = tb / HWn;
  int tid = threadIdx.x;
  for (int i = tid; i < 2176; i += 256) kvs[i] = kvfin[n*2176 + i];
  {
    const float4* qsrc = (const float4*)&Q[(size_t)tb*128];
    float4* qdst = (float4*)&qs[0][0];
#pragma unroll
    for (int r = 0; r < 4; r++) qdst[r*256 + tid] = qsrc[r*256 + tid];
  }
  __syncthreads();
  int c = tid & 127, tq = tid >> 7;
  int h = c >> 4, m = c & 15;
  float kvm[16], ksd[16];
#pragma unroll
  for (int d = 0; d < 16; d++){
    kvm[d] = kvs[h*272 + m*16 + d];
    ksd[d] = kvs[h*272 + 256 + d];
  }
#pragma unroll 2
  for (int r = 0; r < 16; r++){
    int t = r*2 + tq;
    float num = 0.f, den = 0.f;
#pragma unroll
    for (int d = 0; d < 16; d++){
      float qv = qs[t][h*16 + d];
      num += qv * kvm[d];
      den += qv * ksd[d];
    }
    Vout[(size_t)(tb + t)*128 + c] = num / (den + 1e-6f);
  }
}

// ---------------- homography warp + bilinear sample (pixel-major ctx) ----------------
__global__ __launch_bounds__(128) void k_warp(const float* __restrict__ ctxref, const float* __restrict__ depth,
     const float* __restrict__ projs, float* __restrict__ ctxsrc){
  int bi = blockIdx.x; int n = bi / HWn; int p = bi - n*HWn;
  int y = p / WW, x = p - y*WW;
  const float* pr = &projs[n*12];
  float d = depth[n*HWn + p];
  float fx = (float)x, fy = (float)y;
  float px = (pr[0]*fx + pr[1]*fy + pr[2])*d + pr[9];
  float py = (pr[3]*fx + pr[4]*fy + pr[5])*d + pr[10];
  float pz = (pr[6]*fx + pr[7]*fy + pr[8])*d + pr[11];
  if (pz == 0.f) pz = 1e-9f;
  float xs = px/pz, ys = py/pz;
  float x0 = floorf(xs), y0 = floorf(ys);
  float wx = xs - x0, wy = ys - y0;
  int c = threadIdx.x;
  float acc = 0.f;
#pragma unroll
  for (int dy = 0; dy < 2; dy++){
    float cy = y0 + dy;
    float wyv = dy ? wy : 1.f - wy;
#pragma unroll
    for (int dx = 0; dx < 2; dx++){
      float cx = x0 + dx;
      float wxv = dx ? wx : 1.f - wx;
      bool valid = (cx >= 0.f) && (cx <= (float)(WW-1)) && (cy >= 0.f) && (cy <= (float)(HH-1));
      int xi = (int)fminf(fmaxf(cx, 0.f), (float)(WW-1));
      int yi = (int)fminf(fmaxf(cy, 0.f), (float)(HH-1));
      float v = ctxref[((size_t)(n*HWn) + yi*WW + xi)*128 + c];
      acc += valid ? wxv*wyv*v : 0.f;
    }
  }
  ctxsrc[(size_t)bi*128 + c] = acc;
}

// ---------------- token build: transpose feature + PE + ctx ----------------
__global__ __launch_bounds__(256) void k_build(const float* __restrict__ feat, const float* __restrict__ ctx,
      float* __restrict__ out){
  __shared__ float tile[32][33];
  int tx = threadIdx.x, ty = threadIdx.y;
  int p0 = blockIdx.x*32, c0 = blockIdx.y*32, b = blockIdx.z;
  for (int i = ty; i < 32; i += 8)
    tile[i][tx] = feat[((size_t)(b*CD + c0 + i))*HWn + p0 + tx];
  __syncthreads();
  const float LOG1E4_32 = 0.28782313662425572f;  // ln(10000)/32
  for (int r = ty; r < 32; r += 8){
    int p = p0 + r, c = c0 + tx;
    int y = p / WW, x = p - y*WW;
    int i = c >> 2, j = c & 3;
    float dv = expf(-(float)i * LOG1E4_32);
    float pos = (j < 2) ? (float)(x + 1) : (float)(y + 1);
    float arg = pos * dv;
    float pe = (j & 1) ? cosf(arg) : sinf(arg);
    size_t o = ((size_t)(b*HWn) + p)*128 + c;
    out[o] = tile[tx][r] + pe + ctx[o];
  }
}

// ---------------- host ----------------
extern "C" void kernel_launch(void* const* d_in, const int* in_sizes, int n_in,
                              void* d_out, int out_size, void* d_ws, size_t ws_size,
                              hipStream_t stream) {
  const float* ref_feature = (const float*)d_in[0];
  const float* src_feature = (const float*)d_in[1];
  const float* ref_proj    = (const float*)d_in[2];
  const float* ref_i2w     = (const float*)d_in[4];
  const float* src_i2w     = (const float*)d_in[5];
  const float* depth       = (const float*)d_in[6];
  const float* attn_w      = (const float*)d_in[7];
  const float* attn_b      = (const float*)d_in[8];
  const float* ffn_w1      = (const float*)d_in[9];
  const float* ffn_b1      = (const float*)d_in[10];
  const float* ffn_w2      = (const float*)d_in[11];
  const float* ffn_b2      = (const float*)d_in[12];
  const float* ln_g        = (const float*)d_in[13];
  const float* ln_b        = (const float*)d_in[14];
  const float* rc_w        = (const float*)d_in[15];
  const float* rc_b        = (const float*)d_in[16];
  const float* bn2_g       = (const float*)d_in[17];
  const float* bn2_b       = (const float*)d_in[18];
  const float* cc_w        = (const float*)d_in[19];
  const float* cc_b        = (const float*)d_in[20];
  const float* bn1_g       = (const float*)d_in[21];
  const float* bn1_b       = (const float*)d_in[22];
  const float* fc1_w       = (const float*)d_in[23];
  const float* fc1_b       = (const float*)d_in[24];
  const float* fc2_w       = (const float*)d_in[25];
  const float* fc2_b       = (const float*)d_in[26];
  const float* ser_w       = (const float*)d_in[27];
  const float* ser_b       = (const float*)d_in[28];
  const float* see_w       = (const float*)d_in[29];
  const float* see_b       = (const float*)d_in[30];

  // ws layout: 3 token buffers + small partials (~64.3 MB total)
  float* ws = (float*)d_ws;
  float* QB = ws;                   // TOKN
  float* KB = QB + TOKN;            // TOKN (K, then attnV out; FFN hidden spans KB+VB)
  float* VB = KB + TOKN;            // TOKN
  float* KVPART = VB + TOKN;        // 1280*272
  float* KVFIN  = KVPART + 1280*272;// 16*272
  float* PROJ   = KVFIN + 16*272;   // 24 (pad 32)
  float* GATE   = PROJ + 32;        // 256
  // ref/src token streams live in d_out for the whole network
  float* Rm = (float*)d_out;        // TOKN
  float* Sm = Rm + TOKN;            // TOKN

  // preamble
  k_small<<<1, 256, 0, stream>>>(ref_proj, src_i2w, ref_i2w, bn1_g, bn1_b, fc1_w, fc1_b,
                                 fc2_w, fc2_b, ser_w, ser_b, see_w, see_b, PROJ, GATE);
  k_hmap<<<TT, 128, 0, stream>>>(depth, rc_w, rc_b, bn2_g, bn2_b, GATE, QB);
  k_gemm<0,0><<<dim3(TT/32, 1), 256, 0, stream>>>(QB, cc_w, cc_b, nullptr, KB, 128, 128, 128, nullptr, nullptr);
  k_warp<<<TT, 128, 0, stream>>>(KB, depth, PROJ, VB);
  k_build<<<dim3(HWn/32, 4, BN), dim3(32, 8), 0, stream>>>(ref_feature, KB, Rm);
  k_build<<<dim3(HWn/32, 4, BN), dim3(32, 8), 0, stream>>>(src_feature, VB, Sm);

  // in-place encoder; kernels are stream-serialized.
  auto enc = [&](float* x, const float* srcp, int l){
    const float* W  = attn_w + (size_t)l*4*16384;
    const float* Bv = attn_b + (size_t)l*4*128;
    const float* g0 = ln_g + (size_t)l*256, *b0 = ln_b + (size_t)l*256;
    k_gemm<2,0><<<dim3(TT/32, 1), 256, 0, stream>>>(x,    W + 0*16384, Bv + 0,   nullptr, QB, 128, 128, 128, nullptr, nullptr);
    k_gemm<2,0><<<dim3(TT/32, 1), 256, 0, stream>>>(srcp, W + 1*16384, Bv + 128, nullptr, KB, 128, 128, 128, nullptr, nullptr);
    k_gemm<0,0><<<dim3(TT/32, 1), 256, 0, stream>>>(srcp, W + 2*16384, Bv + 256, nullptr, VB, 128, 128, 128, nullptr, nullptr);
    k_kvpart<<<1280, 256, 0, stream>>>(KB, VB, KVPART);
    k_kvreduce<<<16, 320, 0, stream>>>(KVPART, KVFIN);
    k_attnv<<<TT/32, 256, 0, stream>>>(QB, KVFIN, KB);
    // out-proj + residual + LN0 fused
    k_gemm<0,1><<<dim3(TT/32, 1), 256, 0, stream>>>(KB, W + 3*16384, Bv + 3*128, x, QB, 128, 128, 128, g0, b0);
    // FFN
    k_gemm<1,0><<<dim3(TT/32, 2), 256, 0, stream>>>(QB, ffn_w1 + (size_t)l*128*256, ffn_b1 + (size_t)l*256,
                                                    nullptr, KB, 128, 256, 256, nullptr, nullptr);
    k_gemm<0,1><<<dim3(TT/32, 1), 256, 0, stream>>>(KB, ffn_w2 + (size_t)l*256*128, ffn_b2 + (size_t)l*128,
                                                    QB, x, 256, 128, 128, g0 + 128, b0 + 128);
  };

  // layer 0: self
  enc(Rm, Rm, 0); enc(Sm, Sm, 0);
  // layer 1: cross (src uses updated ref)
  enc(Rm, Sm, 1); enc(Sm, Rm, 1);
  // layer 2: self
  enc(Rm, Rm, 2); enc(Sm, Sm, 2);
  // layer 3: cross, final results land in d_out
  enc(Rm, Sm, 3); enc(Sm, Rm, 3);
}

// Round 7
// 1611.405 us; speedup vs baseline: 2.0809x; 1.2589x over previous
//
#include <hip/hip_runtime.h>
#include <math.h>

#define BN 2
#define HH 128
#define WW 160
#define HWn (HH*WW)          // 20480
#define CD 128
#define TT (BN*HWn)          // 40960 tokens per stream
#define TOKN ((size_t)TT*CD) // 5,242,880 elements

typedef __attribute__((ext_vector_type(8))) short bf16x8;
typedef __attribute__((ext_vector_type(4))) short bf16x4;
typedef __attribute__((ext_vector_type(4))) float f32x4;
typedef __attribute__((ext_vector_type(4))) unsigned short u16x4;

__device__ __forceinline__ float b2f(unsigned short s){
  unsigned u = ((unsigned)s) << 16;
  return __builtin_bit_cast(float, u);
}
__device__ __forceinline__ unsigned short f2b(float f){
  unsigned u = __builtin_bit_cast(unsigned, f);
  u = (u + 0x7fffu + ((u >> 16) & 1u)) >> 16;   // RNE
  return (unsigned short)u;
}

// ---------------- K0: tiny precompute: proj mats + SE gate ----------------
__global__ void k_small(const float* __restrict__ ref_proj, const float* __restrict__ src_i2w,
                        const float* __restrict__ cam16,
                        const float* __restrict__ bn1_g, const float* __restrict__ bn1_b,
                        const float* __restrict__ fc1_w, const float* __restrict__ fc1_b,
                        const float* __restrict__ fc2_w, const float* __restrict__ fc2_b,
                        const float* __restrict__ ser_w, const float* __restrict__ ser_b,
                        const float* __restrict__ see_w, const float* __restrict__ see_b,
                        float* __restrict__ projsmall, float* __restrict__ gate){
  __shared__ float mi[BN][16], t1[BN][128], t2[BN][128];
  int tid = threadIdx.x;
  const float inv_std = rsqrtf(1.0f + 1e-5f);
  if (tid < 32){
    int b = tid >> 4, idx = tid & 15, i = idx >> 2, k = idx & 3;
    float acc = 0.f;
    for (int j = 0; j < 4; j++) acc += ref_proj[b*16 + i*4 + j] * src_i2w[b*16 + j*4 + k];
    if (i < 3 && k < 3) projsmall[b*12 + i*3 + k] = acc;
    if (i < 3 && k == 3) projsmall[b*12 + 9 + i] = acc;
    mi[b][idx] = cam16[b*16 + idx] * inv_std * bn1_g[idx] + bn1_b[idx];
  }
  __syncthreads();
  int b = tid >> 7, c = tid & 127;
  float a = 0.f;
  for (int j = 0; j < 16; j++) a += mi[b][j] * fc1_w[j*128 + c];
  t1[b][c] = fmaxf(a + fc1_b[c], 0.f);
  __syncthreads();
  a = 0.f;
  for (int k = 0; k < 128; k++) a += t1[b][k] * fc2_w[k*128 + c];
  t2[b][c] = a + fc2_b[c];
  __syncthreads();
  a = 0.f;
  for (int k = 0; k < 128; k++) a += t2[b][k] * ser_w[k*128 + c];
  t1[b][c] = fmaxf(a + ser_b[c], 0.f);
  __syncthreads();
  a = 0.f;
  for (int k = 0; k < 128; k++) a += t1[b][k] * see_w[k*128 + c];
  a += see_b[c];
  gate[b*128 + c] = 1.f / (1.f + expf(-a));
}

// ---------------- weight convert: f32 -> bf16, transposed Wt[n][k] ----------------
__global__ __launch_bounds__(256) void k_wconv(const float* __restrict__ attn_w,
      const float* __restrict__ ffn_w1, const float* __restrict__ ffn_w2,
      const float* __restrict__ cc_w, unsigned short* __restrict__ wt){
  int i = blockIdx.x*256 + threadIdx.x;
  float v;
  if (i < 262144){                       // attn: [(l*4+m)][n][k] <- attn_w[lm][k][n]
    int k = i & 127, n = (i >> 7) & 127, lm = i >> 14;
    v = attn_w[((size_t)lm*128 + k)*128 + n];
  } else if (i < 393216){ int j = i - 262144;   // f1t: [l][n<256][k<128]
    int k = j & 127, n = (j >> 7) & 255, l = j >> 15;
    v = ffn_w1[((size_t)l*128 + k)*256 + n];
  } else if (i < 524288){ int j = i - 393216;   // f2t: [l][n<128][k<256]
    int k = j & 255, n = (j >> 8) & 127, l = j >> 15;
    v = ffn_w2[((size_t)l*256 + k)*128 + n];
  } else if (i < 540672){ int j = i - 524288;   // cct: [o][c] <- cc_w[c][o]
    int k = j & 127, n = j >> 7;
    v = cc_w[(size_t)k*128 + n];
  } else return;
  wt[i] = f2b(v);
}

// ---------------- K1: conv3x3(depth) + bn + relu + gate, pixel-major, bf16 out ----------------
__global__ __launch_bounds__(128) void k_hmap(const float* __restrict__ depth,
                       const float* __restrict__ rc_w, const float* __restrict__ rc_b,
                       const float* __restrict__ bn2_g, const float* __restrict__ bn2_b,
                       const float* __restrict__ gate, unsigned short* __restrict__ G){
  int bi = blockIdx.x; int n = bi / HWn; int p = bi - n*HWn;
  int y = p / WW, x = p - y*WW;
  int c = threadIdx.x;
  const float inv_std = rsqrtf(1.f + 1e-5f);
  float acc = 0.f;
#pragma unroll
  for (int ky = 0; ky < 3; ky++){
    int yy = y + ky - 1;
#pragma unroll
    for (int kx = 0; kx < 3; kx++){
      int xx = x + kx - 1;
      float v = (yy >= 0 && yy < HH && xx >= 0 && xx < WW) ? depth[n*HWn + yy*WW + xx] : 0.f;
      acc += v * rc_w[c*9 + ky*3 + kx];
    }
  }
  acc += rc_b[c];
  acc = fmaxf(acc * inv_std * bn2_g[c] + bn2_b[c], 0.f);
  G[(size_t)bi*128 + c] = f2b(acc * gate[n*128 + c]);
}

// ---- bf16 MFMA GEMM: C[T,N] = [LN](act(A[T,K] @ W + bias (+resid))) ----
// Wt is pre-transposed bf16 [Ntot][K]. Block = 256 thr = 4 waves; 64 tokens/block.
// Each wave: 16 tokens x 128 cols via mfma_f32_16x16x32_bf16 (operands: W-frag, A-frag).
template<int ACT, int LN>  // ACT: 0 none, 1 relu, 2 elu+1
__global__ __launch_bounds__(256) void k_bgemm(
    const unsigned short* __restrict__ A, const unsigned short* __restrict__ Wt,
    const float* __restrict__ bias, const unsigned short* __restrict__ resid,
    unsigned short* __restrict__ C, int K, int ldC,
    const float* __restrict__ lng, const float* __restrict__ lnb){
  int tid = threadIdx.x;
  int wid = tid >> 6, lane = tid & 63;
  int t0 = blockIdx.x*64 + wid*16;
  int col0 = blockIdx.y*128;
  int r = lane & 15, ks = lane >> 4;           // token-in-frag / k-segment
  const unsigned short* ap = A + (size_t)(t0 + r)*K + ks*8;
  f32x4 acc[8] = {};
  for (int kc = 0; kc < K; kc += 32){
    bf16x8 a = *(const bf16x8*)(ap + kc);
#pragma unroll
    for (int f = 0; f < 8; f++){
      bf16x8 w = *(const bf16x8*)(Wt + (size_t)(col0 + f*16 + r)*K + kc + ks*8);
      acc[f] = __builtin_amdgcn_mfma_f32_16x16x32_bf16(w, a, acc[f], 0, 0, 0);
    }
  }
  // lane holds token t0+r, cols col0 + f*16 + 4*ks + e  (e=0..3)
  size_t trow = (size_t)(t0 + r);
  float vv[8][4];
#pragma unroll
  for (int f = 0; f < 8; f++){
    float4 bi = *(const float4*)&bias[col0 + f*16 + 4*ks];
    vv[f][0] = acc[f][0] + bi.x; vv[f][1] = acc[f][1] + bi.y;
    vv[f][2] = acc[f][2] + bi.z; vv[f][3] = acc[f][3] + bi.w;
    if (resid){
      u16x4 rr = *(const u16x4*)(resid + trow*128 + f*16 + 4*ks);
#pragma unroll
      for (int e = 0; e < 4; e++) vv[f][e] += b2f(rr[e]);
    }
#pragma unroll
    for (int e = 0; e < 4; e++){
      float x = vv[f][e];
      if (ACT == 1) x = fmaxf(x, 0.f);
      if (ACT == 2) x = x > 0.f ? x + 1.f : expf(x);
      vv[f][e] = x;
    }
  }
  if (LN){   // N==128, col0==0; row t0+r spread over lanes r, r+16, r+32, r+48
    float s = 0.f;
#pragma unroll
    for (int f = 0; f < 8; f++) s += vv[f][0]+vv[f][1]+vv[f][2]+vv[f][3];
    s += __shfl_xor(s, 16, 64); s += __shfl_xor(s, 32, 64);
    float mean = s * (1.f/128.f);
    float q = 0.f;
#pragma unroll
    for (int f = 0; f < 8; f++)
#pragma unroll
      for (int e = 0; e < 4; e++){ float d = vv[f][e]-mean; q += d*d; }
    q += __shfl_xor(q, 16, 64); q += __shfl_xor(q, 32, 64);
    float rstd = rsqrtf(q*(1.f/128.f) + 1e-5f);
#pragma unroll
    for (int f = 0; f < 8; f++){
      float4 g4 = *(const float4*)&lng[f*16 + 4*ks];
      float4 b4 = *(const float4*)&lnb[f*16 + 4*ks];
      vv[f][0] = (vv[f][0]-mean)*rstd*g4.x + b4.x;
      vv[f][1] = (vv[f][1]-mean)*rstd*g4.y + b4.y;
      vv[f][2] = (vv[f][2]-mean)*rstd*g4.z + b4.z;
      vv[f][3] = (vv[f][3]-mean)*rstd*g4.w + b4.w;
    }
  }
#pragma unroll
  for (int f = 0; f < 8; f++){
    u16x4 o;
#pragma unroll
    for (int e = 0; e < 4; e++) o[e] = f2b(vv[f][e]);
    *(u16x4*)(C + trow*ldC + col0 + f*16 + 4*ks) = o;
  }
}

// ---------------- KV partial: per (n,h,chunk of 256 tokens): 16x16 KV + 16 Ksum ----------------
__global__ __launch_bounds__(256) void k_kvpart(const unsigned short* __restrict__ Kb,
                         const unsigned short* __restrict__ Vb, float* __restrict__ part){
  __shared__ float Ks[256][16], Vs[256][16];
  int bi = blockIdx.x;
  int chunk = bi % 80; int h = (bi / 80) & 7; int n = bi / 640;
  int s0 = chunk * 256;
  int tid = threadIdx.x;
#pragma unroll
  for (int r = 0; r < 8; r++){
    int idx = r*256 + tid;             // ushort2 index
    int s = idx >> 3, d2 = idx & 7;
    size_t g = ((size_t)(n*HWn + s0 + s))*128 + h*16 + d2*2;
    Ks[s][d2*2]   = b2f(Kb[g]);
    Ks[s][d2*2+1] = b2f(Kb[g+1]);
    Vs[s][d2*2]   = b2f(Vb[g]);
    Vs[s][d2*2+1] = b2f(Vb[g+1]);
  }
  __syncthreads();
  int m = tid >> 4, d = tid & 15;
  float acc = 0.f;
  for (int s = 0; s < 256; s++) acc += Ks[s][d] * Vs[s][m];
  part[(size_t)bi*272 + tid] = acc;
  if (m == 0){
    float ks = 0.f;
    for (int s = 0; s < 256; s++) ks += Ks[s][d];
    part[(size_t)bi*272 + 256 + d] = ks;
  }
}

__global__ void k_kvreduce(const float* __restrict__ part, float* __restrict__ fin){
  int nh = blockIdx.x;
  int o = threadIdx.x;
  if (o < 272){
    float acc = 0.f;
    for (int c2 = 0; c2 < 80; c2++) acc += part[((size_t)nh*80 + c2)*272 + o];
    fin[nh*272 + o] = acc;
  }
}

// ---------------- attention V: V[t,c] = Q[t,h,:]·KV[h,m,:] / (Q[t,h,:]·Ksum[h,:]+eps) ----------------
__global__ __launch_bounds__(256) void k_attnv(const unsigned short* __restrict__ Q,
      const float* __restrict__ kvfin, unsigned short* __restrict__ Vout){
  __shared__ float kvs[2176];       // 8 heads x 272
  __shared__ float qs[32][128];
  int tb = blockIdx.x * 32;
  int n = tb / HWn;
  int tid = threadIdx.x;
  for (int i = tid; i < 2176; i += 256) kvs[i] = kvfin[n*2176 + i];
  {
    const u16x4* qsrc = (const u16x4*)&Q[(size_t)tb*128];
#pragma unroll
    for (int r = 0; r < 4; r++){       // 32*128/4 = 1024 u16x4 total
      int i4 = r*256 + tid;
      u16x4 v = qsrc[i4];
      int row = i4 >> 5, c0 = (i4 & 31)*4;
#pragma unroll
      for (int e = 0; e < 4; e++) qs[row][c0+e] = b2f(v[e]);
    }
  }
  __syncthreads();
  int c = tid & 127, tq = tid >> 7;
  int h = c >> 4, m = c & 15;
  float kvm[16], ksd[16];
#pragma unroll
  for (int d = 0; d < 16; d++){
    kvm[d] = kvs[h*272 + m*16 + d];
    ksd[d] = kvs[h*272 + 256 + d];
  }
#pragma unroll 2
  for (int r = 0; r < 16; r++){
    int t = r*2 + tq;
    float num = 0.f, den = 0.f;
#pragma unroll
    for (int d = 0; d < 16; d++){
      float qv = qs[t][h*16 + d];
      num += qv * kvm[d];
      den += qv * ksd[d];
    }
    Vout[(size_t)(tb + t)*128 + c] = f2b(num / (den + 1e-6f));
  }
}

// ---------------- homography warp + bilinear sample (pixel-major ctx, bf16) ----------------
__global__ __launch_bounds__(128) void k_warp(const unsigned short* __restrict__ ctxref,
     const float* __restrict__ depth, const float* __restrict__ projs,
     unsigned short* __restrict__ ctxsrc){
  int bi = blockIdx.x; int n = bi / HWn; int p = bi - n*HWn;
  int y = p / WW, x = p - y*WW;
  const float* pr = &projs[n*12];
  float d = depth[n*HWn + p];
  float fx = (float)x, fy = (float)y;
  float px = (pr[0]*fx + pr[1]*fy + pr[2])*d + pr[9];
  float py = (pr[3]*fx + pr[4]*fy + pr[5])*d + pr[10];
  float pz = (pr[6]*fx + pr[7]*fy + pr[8])*d + pr[11];
  if (pz == 0.f) pz = 1e-9f;
  float xs = px/pz, ys = py/pz;
  float x0 = floorf(xs), y0 = floorf(ys);
  float wx = xs - x0, wy = ys - y0;
  int c = threadIdx.x;
  float acc = 0.f;
#pragma unroll
  for (int dy = 0; dy < 2; dy++){
    float cy = y0 + dy;
    float wyv = dy ? wy : 1.f - wy;
#pragma unroll
    for (int dx = 0; dx < 2; dx++){
      float cx = x0 + dx;
      float wxv = dx ? wx : 1.f - wx;
      bool valid = (cx >= 0.f) && (cx <= (float)(WW-1)) && (cy >= 0.f) && (cy <= (float)(HH-1));
      int xi = (int)fminf(fmaxf(cx, 0.f), (float)(WW-1));
      int yi = (int)fminf(fmaxf(cy, 0.f), (float)(HH-1));
      float v = b2f(ctxref[((size_t)(n*HWn) + yi*WW + xi)*128 + c]);
      acc += valid ? wxv*wyv*v : 0.f;
    }
  }
  ctxsrc[(size_t)bi*128 + c] = f2b(acc);
}

// ---------------- token build: transpose feature + PE + ctx, bf16 out ----------------
__global__ __launch_bounds__(256) void k_build(const float* __restrict__ feat,
      const unsigned short* __restrict__ ctx, unsigned short* __restrict__ out){
  __shared__ float tile[32][33];
  int tx = threadIdx.x, ty = threadIdx.y;
  int p0 = blockIdx.x*32, c0 = blockIdx.y*32, b = blockIdx.z;
  for (int i = ty; i < 32; i += 8)
    tile[i][tx] = feat[((size_t)(b*CD + c0 + i))*HWn + p0 + tx];
  __syncthreads();
  const float LOG1E4_32 = 0.28782313662425572f;  // ln(10000)/32
  for (int r = ty; r < 32; r += 8){
    int p = p0 + r, c = c0 + tx;
    int y = p / WW, x = p - y*WW;
    int i = c >> 2, j = c & 3;
    float dv = expf(-(float)i * LOG1E4_32);
    float pos = (j < 2) ? (float)(x + 1) : (float)(y + 1);
    float arg = pos * dv;
    float pe = (j & 1) ? cosf(arg) : sinf(arg);
    size_t o = ((size_t)(b*HWn) + p)*128 + c;
    out[o] = f2b(tile[tx][r] + pe + b2f(ctx[o]));
  }
}

// ---------------- final: bf16 streams -> f32 d_out ----------------
__global__ __launch_bounds__(256) void k_tofp32(const unsigned short* __restrict__ s,
                                                float* __restrict__ out){
  size_t i = ((size_t)blockIdx.x*256 + threadIdx.x)*4;
  u16x4 v = *(const u16x4*)(s + i);
  float4 o = { b2f(v[0]), b2f(v[1]), b2f(v[2]), b2f(v[3]) };
  *(float4*)(out + i) = o;
}

// ---------------- host ----------------
extern "C" void kernel_launch(void* const* d_in, const int* in_sizes, int n_in,
                              void* d_out, int out_size, void* d_ws, size_t ws_size,
                              hipStream_t stream) {
  const float* ref_feature = (const float*)d_in[0];
  const float* src_feature = (const float*)d_in[1];
  const float* ref_proj    = (const float*)d_in[2];
  const float* ref_i2w     = (const float*)d_in[4];
  const float* src_i2w     = (const float*)d_in[5];
  const float* depth       = (const float*)d_in[6];
  const float* attn_w      = (const float*)d_in[7];
  const float* attn_b      = (const float*)d_in[8];
  const float* ffn_w1      = (const float*)d_in[9];
  const float* ffn_b1      = (const float*)d_in[10];
  const float* ffn_w2      = (const float*)d_in[11];
  const float* ffn_b2      = (const float*)d_in[12];
  const float* ln_g        = (const float*)d_in[13];
  const float* ln_b        = (const float*)d_in[14];
  const float* rc_w        = (const float*)d_in[15];
  const float* rc_b        = (const float*)d_in[16];
  const float* bn2_g       = (const float*)d_in[17];
  const float* bn2_b       = (const float*)d_in[18];
  const float* cc_w        = (const float*)d_in[19];
  const float* cc_b        = (const float*)d_in[20];
  const float* bn1_g       = (const float*)d_in[21];
  const float* bn1_b       = (const float*)d_in[22];
  const float* fc1_w       = (const float*)d_in[23];
  const float* fc1_b       = (const float*)d_in[24];
  const float* fc2_w       = (const float*)d_in[25];
  const float* fc2_b       = (const float*)d_in[26];
  const float* ser_w       = (const float*)d_in[27];
  const float* ser_b       = (const float*)d_in[28];
  const float* see_w       = (const float*)d_in[29];
  const float* see_b       = (const float*)d_in[30];

  // ws layout (~55 MB): 5 bf16 token buffers + partials + bf16 weights
  char* p = (char*)d_ws;
  unsigned short* Rm = (unsigned short*)p; p += TOKN*2;
  unsigned short* Sm = (unsigned short*)p; p += TOKN*2;
  unsigned short* QB = (unsigned short*)p; p += TOKN*2;
  unsigned short* KB = (unsigned short*)p; p += TOKN*2;   // KB..VB contiguous = FFN hidden [T][256]
  unsigned short* VB = (unsigned short*)p; p += TOKN*2;
  float* KVPART = (float*)p; p += (size_t)1280*272*4;
  float* KVFIN  = (float*)p; p += 16*272*4;
  float* PROJ   = (float*)p; p += 32*4;
  float* GATE   = (float*)p; p += 256*4;
  unsigned short* WT = (unsigned short*)p;                 // 540672 bf16
  unsigned short* H  = KB;                                 // FFN hidden alias

  float* OUT = (float*)d_out;

  // weight conversion (bf16, transposed)
  k_wconv<<<2112, 256, 0, stream>>>(attn_w, ffn_w1, ffn_w2, cc_w, WT);
  // preamble
  k_small<<<1, 256, 0, stream>>>(ref_proj, src_i2w, ref_i2w, bn1_g, bn1_b, fc1_w, fc1_b,
                                 fc2_w, fc2_b, ser_w, ser_b, see_w, see_b, PROJ, GATE);
  k_hmap<<<TT, 128, 0, stream>>>(depth, rc_w, rc_b, bn2_g, bn2_b, GATE, QB);
  k_bgemm<0,0><<<dim3(TT/64, 1), 256, 0, stream>>>(QB, WT + 524288, cc_b, nullptr, KB, 128, 128, nullptr, nullptr);
  k_warp<<<TT, 128, 0, stream>>>(KB, depth, PROJ, VB);
  k_build<<<dim3(HWn/32, 4, BN), dim3(32, 8), 0, stream>>>(ref_feature, KB, Rm);
  k_build<<<dim3(HWn/32, 4, BN), dim3(32, 8), 0, stream>>>(src_feature, VB, Sm);

  // in-place encoder; kernels are stream-serialized.
  auto enc = [&](unsigned short* x, const unsigned short* srcp, int l){
    const unsigned short* ATW = WT + (size_t)l*65536;          // 4 x [128][128]
    const unsigned short* F1T = WT + 262144 + (size_t)l*32768; // [256][128]
    const unsigned short* F2T = WT + 393216 + (size_t)l*32768; // [128][256]
    const float* Bv = attn_b + (size_t)l*4*128;
    const float* g0 = ln_g + (size_t)l*256, *b0 = ln_b + (size_t)l*256;
    k_bgemm<2,0><<<dim3(TT/64, 1), 256, 0, stream>>>(x,    ATW + 0*16384, Bv + 0,   nullptr, QB, 128, 128, nullptr, nullptr);
    k_bgemm<2,0><<<dim3(TT/64, 1), 256, 0, stream>>>(srcp, ATW + 1*16384, Bv + 128, nullptr, KB, 128, 128, nullptr, nullptr);
    k_bgemm<0,0><<<dim3(TT/64, 1), 256, 0, stream>>>(srcp, ATW + 2*16384, Bv + 256, nullptr, VB, 128, 128, nullptr, nullptr);
    k_kvpart<<<1280, 256, 0, stream>>>(KB, VB, KVPART);
    k_kvreduce<<<16, 320, 0, stream>>>(KVPART, KVFIN);
    k_attnv<<<TT/32, 256, 0, stream>>>(QB, KVFIN, KB);
    // out-proj + residual + LN0 fused
    k_bgemm<0,1><<<dim3(TT/64, 1), 256, 0, stream>>>(KB, ATW + 3*16384, Bv + 3*128, x, QB, 128, 128, g0, b0);
    // FFN
    k_bgemm<1,0><<<dim3(TT/64, 2), 256, 0, stream>>>(QB, F1T, ffn_b1 + (size_t)l*256, nullptr, H, 128, 256, nullptr, nullptr);
    k_bgemm<0,1><<<dim3(TT/64, 1), 256, 0, stream>>>(H, F2T, ffn_b2 + (size_t)l*128, QB, x, 256, 128, g0 + 128, b0 + 128);
  };

  // layer 0: self
  enc(Rm, Rm, 0); enc(Sm, Sm, 0);
  // layer 1: cross (src uses updated ref)
  enc(Rm, Sm, 1); enc(Sm, Rm, 1);
  // layer 2: self
  enc(Rm, Rm, 2); enc(Sm, Sm, 2);
  // layer 3: cross
  enc(Rm, Sm, 3); enc(Sm, Rm, 3);

  // convert both streams (contiguous Rm|Sm) to f32 output
  k_tofp32<<<(unsigned)(2*TOKN/(256*4)), 256, 0, stream>>>(Rm, OUT);
}

// Round 9
// 1300.426 us; speedup vs baseline: 2.5785x; 1.2391x over previous
//
#include <hip/hip_runtime.h>
#include <math.h>

#define BN 2
#define HH 128
#define WW 160
#define HWn (HH*WW)          // 20480
#define CD 128
#define TT (BN*HWn)          // 40960 tokens per stream
#define TOKN ((size_t)TT*CD) // 5,242,880 elements

typedef __attribute__((ext_vector_type(8))) short bf16x8;
typedef __attribute__((ext_vector_type(4))) float f32x4;
typedef __attribute__((ext_vector_type(4))) unsigned short u16x4;

__device__ __forceinline__ float b2f(unsigned short s){
  unsigned u = ((unsigned)s) << 16;
  return __builtin_bit_cast(float, u);
}
__device__ __forceinline__ unsigned short f2b(float f){
  unsigned u = __builtin_bit_cast(unsigned, f);
  u = (u + 0x7fffu + ((u >> 16) & 1u)) >> 16;   // RNE
  return (unsigned short)u;
}

// ---------------- K0: tiny precompute: proj mats + SE gate ----------------
__global__ void k_small(const float* __restrict__ ref_proj, const float* __restrict__ src_i2w,
                        const float* __restrict__ cam16,
                        const float* __restrict__ bn1_g, const float* __restrict__ bn1_b,
                        const float* __restrict__ fc1_w, const float* __restrict__ fc1_b,
                        const float* __restrict__ fc2_w, const float* __restrict__ fc2_b,
                        const float* __restrict__ ser_w, const float* __restrict__ ser_b,
                        const float* __restrict__ see_w, const float* __restrict__ see_b,
                        float* __restrict__ projsmall, float* __restrict__ gate){
  __shared__ float mi[BN][16], t1[BN][128], t2[BN][128];
  int tid = threadIdx.x;
  const float inv_std = rsqrtf(1.0f + 1e-5f);
  if (tid < 32){
    int b = tid >> 4, idx = tid & 15, i = idx >> 2, k = idx & 3;
    float acc = 0.f;
    for (int j = 0; j < 4; j++) acc += ref_proj[b*16 + i*4 + j] * src_i2w[b*16 + j*4 + k];
    if (i < 3 && k < 3) projsmall[b*12 + i*3 + k] = acc;
    if (i < 3 && k == 3) projsmall[b*12 + 9 + i] = acc;
    mi[b][idx] = cam16[b*16 + idx] * inv_std * bn1_g[idx] + bn1_b[idx];
  }
  __syncthreads();
  int b = tid >> 7, c = tid & 127;
  float a = 0.f;
  for (int j = 0; j < 16; j++) a += mi[b][j] * fc1_w[j*128 + c];
  t1[b][c] = fmaxf(a + fc1_b[c], 0.f);
  __syncthreads();
  a = 0.f;
  for (int k = 0; k < 128; k++) a += t1[b][k] * fc2_w[k*128 + c];
  t2[b][c] = a + fc2_b[c];
  __syncthreads();
  a = 0.f;
  for (int k = 0; k < 128; k++) a += t2[b][k] * ser_w[k*128 + c];
  t1[b][c] = fmaxf(a + ser_b[c], 0.f);
  __syncthreads();
  a = 0.f;
  for (int k = 0; k < 128; k++) a += t1[b][k] * see_w[k*128 + c];
  a += see_b[c];
  gate[b*128 + c] = 1.f / (1.f + expf(-a));
}

// ---------------- weight convert: f32 -> bf16, transposed Wt[n][k] ----------------
__global__ __launch_bounds__(256) void k_wconv(const float* __restrict__ attn_w,
      const float* __restrict__ ffn_w1, const float* __restrict__ ffn_w2,
      const float* __restrict__ cc_w, unsigned short* __restrict__ wt){
  int i = blockIdx.x*256 + threadIdx.x;
  float v;
  if (i < 262144){                       // attn: [(l*4+m)][n][k] <- attn_w[lm][k][n]
    int k = i & 127, n = (i >> 7) & 127, lm = i >> 14;
    v = attn_w[((size_t)lm*128 + k)*128 + n];
  } else if (i < 393216){ int j = i - 262144;   // f1t: [l][n<256][k<128]
    int k = j & 127, n = (j >> 7) & 255, l = j >> 15;
    v = ffn_w1[((size_t)l*128 + k)*256 + n];
  } else if (i < 524288){ int j = i - 393216;   // f2t: [l][n<128][k<256]
    int k = j & 255, n = (j >> 8) & 127, l = j >> 15;
    v = ffn_w2[((size_t)l*256 + k)*128 + n];
  } else if (i < 540672){ int j = i - 524288;   // cct: [o][c] <- cc_w[c][o]
    int k = j & 127, n = j >> 7;
    v = cc_w[(size_t)k*128 + n];
  } else return;
  wt[i] = f2b(v);
}

// ---------------- K1: conv3x3(depth) + bn + relu + gate, pixel-major, bf16 out ----------------
__global__ __launch_bounds__(128) void k_hmap(const float* __restrict__ depth,
                       const float* __restrict__ rc_w, const float* __restrict__ rc_b,
                       const float* __restrict__ bn2_g, const float* __restrict__ bn2_b,
                       const float* __restrict__ gate, unsigned short* __restrict__ G){
  int bi = blockIdx.x; int n = bi / HWn; int p = bi - n*HWn;
  int y = p / WW, x = p - y*WW;
  int c = threadIdx.x;
  const float inv_std = rsqrtf(1.f + 1e-5f);
  float acc = 0.f;
#pragma unroll
  for (int ky = 0; ky < 3; ky++){
    int yy = y + ky - 1;
#pragma unroll
    for (int kx = 0; kx < 3; kx++){
      int xx = x + kx - 1;
      float v = (yy >= 0 && yy < HH && xx >= 0 && xx < WW) ? depth[n*HWn + yy*WW + xx] : 0.f;
      acc += v * rc_w[c*9 + ky*3 + kx];
    }
  }
  acc += rc_b[c];
  acc = fmaxf(acc * inv_std * bn2_g[c] + bn2_b[c], 0.f);
  G[(size_t)bi*128 + c] = f2b(acc * gate[n*128 + c]);
}

// ---- QKV GEMM: per section s (grid.y): C_s = act_s(A @ W_s + b_s), K=N=128 ----
// Wt sections contiguous [sec][128][128] (n-major), bias sections contiguous.
__global__ __launch_bounds__(256) void k_bqkv(
    const unsigned short* __restrict__ A, const unsigned short* __restrict__ Wt,
    const float* __restrict__ bias, unsigned short* __restrict__ Cbase,
    size_t CSEG, int amask){
  int tid = threadIdx.x;
  int wid = tid >> 6, lane = tid & 63;
  size_t t0 = (size_t)blockIdx.x*64 + wid*16;
  int sec = blockIdx.y;
  const unsigned short* Ws = Wt + (size_t)sec*16384;
  const float* bs = bias + sec*128;
  unsigned short* C = Cbase + (size_t)sec*CSEG;
  int r = lane & 15, ks = lane >> 4;
  const unsigned short* ap = A + (t0 + r)*128 + ks*8;
  f32x4 acc[8] = {};
  for (int kc = 0; kc < 128; kc += 32){
    bf16x8 a = *(const bf16x8*)(ap + kc);
#pragma unroll
    for (int f = 0; f < 8; f++){
      bf16x8 w = *(const bf16x8*)(Ws + (size_t)(f*16 + r)*128 + kc + ks*8);
      acc[f] = __builtin_amdgcn_mfma_f32_16x16x32_bf16(w, a, acc[f], 0, 0, 0);
    }
  }
  bool act = (amask >> sec) & 1;
  size_t trow = t0 + r;
#pragma unroll
  for (int f = 0; f < 8; f++){
    float4 bi4 = *(const float4*)&bs[f*16 + 4*ks];
    float v[4] = {acc[f][0]+bi4.x, acc[f][1]+bi4.y, acc[f][2]+bi4.z, acc[f][3]+bi4.w};
    u16x4 o;
#pragma unroll
    for (int e = 0; e < 4; e++){
      float x = v[e];
      if (act) x = x > 0.f ? x + 1.f : expf(x);   // elu+1
      o[e] = f2b(x);
    }
    *(u16x4*)(C + trow*128 + f*16 + 4*ks) = o;
  }
}

// ---------------- KV partial: per (g, h, chunk of 256 tokens): 16x16 KV + 16 Ksum ----------------
__global__ __launch_bounds__(256) void k_kvpart(const unsigned short* __restrict__ Kb,
                         const unsigned short* __restrict__ Vb, float* __restrict__ part){
  __shared__ float Ks[256][16], Vs[256][16];
  int bi = blockIdx.x;
  int chunk = bi % 80; int h = (bi / 80) & 7; int g = bi / 640;
  int s0 = chunk * 256;
  int tid = threadIdx.x;
#pragma unroll
  for (int r = 0; r < 8; r++){
    int idx = r*256 + tid;             // ushort2 index
    int s = idx >> 3, d2 = idx & 7;
    size_t gg = ((size_t)(g*HWn + s0 + s))*128 + h*16 + d2*2;
    Ks[s][d2*2]   = b2f(Kb[gg]);
    Ks[s][d2*2+1] = b2f(Kb[gg+1]);
    Vs[s][d2*2]   = b2f(Vb[gg]);
    Vs[s][d2*2+1] = b2f(Vb[gg+1]);
  }
  __syncthreads();
  int m = tid >> 4, d = tid & 15;
  float acc = 0.f;
  for (int s = 0; s < 256; s++) acc += Ks[s][d] * Vs[s][m];
  part[(size_t)bi*272 + tid] = acc;
  if (m == 0){
    float ks = 0.f;
    for (int s = 0; s < 256; s++) ks += Ks[s][d];
    part[(size_t)bi*272 + 256 + d] = ks;
  }
}

__global__ void k_kvreduce(const float* __restrict__ part, float* __restrict__ fin){
  int nh = blockIdx.x;
  int o = threadIdx.x;
  if (o < 272){
    float acc = 0.f;
    for (int c2 = 0; c2 < 80; c2++) acc += part[((size_t)nh*80 + c2)*272 + o];
    fin[nh*272 + o] = acc;
  }
}

// ---- fused attention: V = linear-attn(Q,KV); out = LN0(X + V@W3 + b3) ----
// 64 tokens/block, 256 thr. Q may alias Out (block-local RW, barrier-separated).
__global__ __launch_bounds__(256) void k_fattn(
    const unsigned short* __restrict__ Q, const unsigned short* __restrict__ X,
    const float* __restrict__ kvfin, const unsigned short* __restrict__ W3,
    const float* __restrict__ b3, const float* __restrict__ g0, const float* __restrict__ b0,
    unsigned short* __restrict__ Out){
  __shared__ float kvs[2176];
  __shared__ unsigned short qs[64][136];
  __shared__ unsigned short Vs[64][136];
  int tid = threadIdx.x;
  size_t tb = (size_t)blockIdx.x*64;
  int g = (int)(tb / HWn);
  for (int i = tid; i < 2176; i += 256) kvs[i] = kvfin[g*2176 + i];
  {
    const u16x4* qsrc = (const u16x4*)(Q + tb*128);
#pragma unroll
    for (int rr = 0; rr < 8; rr++){
      int i4 = rr*256 + tid;           // 2048 = 64*128/4
      u16x4 v = qsrc[i4];
      int row = i4 >> 5, c4 = (i4 & 31)*4;
      *(u16x4*)&qs[row][c4] = v;
    }
  }
  __syncthreads();
  {
    int c = tid & 127, tq = tid >> 7;
    int h = c >> 4, m = c & 15;
    float kvm[16], ksd[16];
#pragma unroll
    for (int d = 0; d < 16; d++){
      kvm[d] = kvs[h*272 + m*16 + d];
      ksd[d] = kvs[h*272 + 256 + d];
    }
    for (int rr = 0; rr < 32; rr++){
      int t = rr*2 + tq;
      float num = 0.f, den = 0.f;
#pragma unroll
      for (int d = 0; d < 16; d++){
        float qv = b2f(qs[t][h*16 + d]);
        num += qv * kvm[d];
        den += qv * ksd[d];
      }
      Vs[t][c] = f2b(num / (den + 1e-6f));
    }
  }
  __syncthreads();
  int wid = tid >> 6, lane = tid & 63;
  int r = lane & 15, ks = lane >> 4;
  int tl = wid*16 + r;
  f32x4 acc[8] = {};
  for (int kc = 0; kc < 128; kc += 32){
    bf16x8 a = *(const bf16x8*)&Vs[tl][kc + ks*8];
#pragma unroll
    for (int f = 0; f < 8; f++){
      bf16x8 w = *(const bf16x8*)(W3 + (size_t)(f*16 + r)*128 + kc + ks*8);
      acc[f] = __builtin_amdgcn_mfma_f32_16x16x32_bf16(w, a, acc[f], 0, 0, 0);
    }
  }
  size_t trow = tb + tl;
  float vv[8][4];
#pragma unroll
  for (int f = 0; f < 8; f++){
    float4 bi4 = *(const float4*)&b3[f*16 + 4*ks];
    u16x4 rr = *(const u16x4*)(X + trow*128 + f*16 + 4*ks);
    vv[f][0] = acc[f][0] + bi4.x + b2f(rr[0]);
    vv[f][1] = acc[f][1] + bi4.y + b2f(rr[1]);
    vv[f][2] = acc[f][2] + bi4.z + b2f(rr[2]);
    vv[f][3] = acc[f][3] + bi4.w + b2f(rr[3]);
  }
  float s = 0.f;
#pragma unroll
  for (int f = 0; f < 8; f++) s += vv[f][0]+vv[f][1]+vv[f][2]+vv[f][3];
  s += __shfl_xor(s, 16, 64); s += __shfl_xor(s, 32, 64);
  float mean = s * (1.f/128.f);
  float q = 0.f;
#pragma unroll
  for (int f = 0; f < 8; f++)
#pragma unroll
    for (int e = 0; e < 4; e++){ float d = vv[f][e]-mean; q += d*d; }
  q += __shfl_xor(q, 16, 64); q += __shfl_xor(q, 32, 64);
  float rstd = rsqrtf(q*(1.f/128.f) + 1e-5f);
#pragma unroll
  for (int f = 0; f < 8; f++){
    float4 g4 = *(const float4*)&g0[f*16 + 4*ks];
    float4 b4 = *(const float4*)&b0[f*16 + 4*ks];
    u16x4 o;
    o[0] = f2b((vv[f][0]-mean)*rstd*g4.x + b4.x);
    o[1] = f2b((vv[f][1]-mean)*rstd*g4.y + b4.y);
    o[2] = f2b((vv[f][2]-mean)*rstd*g4.z + b4.z);
    o[3] = f2b((vv[f][3]-mean)*rstd*g4.w + b4.w);
    *(u16x4*)(Out + trow*128 + f*16 + 4*ks) = o;
  }
}

// ---- fused FFN: out = LN1(A + relu(A@W1+b1)@W2 + b2); hidden in LDS ----
__global__ __launch_bounds__(256) void k_fffn(
    const unsigned short* __restrict__ A,
    const unsigned short* __restrict__ W1t, const float* __restrict__ b1,
    const unsigned short* __restrict__ W2t, const float* __restrict__ b2,
    const float* __restrict__ g1, const float* __restrict__ lb1,
    unsigned short* __restrict__ Out){
  __shared__ unsigned short Hs[64][264];
  int tid = threadIdx.x;
  int wid = tid >> 6, lane = tid & 63;
  int r = lane & 15, ks = lane >> 4;
  size_t t0 = (size_t)blockIdx.x*64;
  int tl = wid*16 + r;
  size_t trow = t0 + tl;
  const unsigned short* ap = A + trow*128 + ks*8;
  {
    f32x4 acc[16] = {};
    for (int kc = 0; kc < 128; kc += 32){
      bf16x8 a = *(const bf16x8*)(ap + kc);
#pragma unroll
      for (int f = 0; f < 16; f++){
        bf16x8 w = *(const bf16x8*)(W1t + (size_t)(f*16 + r)*128 + kc + ks*8);
        acc[f] = __builtin_amdgcn_mfma_f32_16x16x32_bf16(w, a, acc[f], 0, 0, 0);
      }
    }
#pragma unroll
    for (int f = 0; f < 16; f++){
      float4 bi4 = *(const float4*)&b1[f*16 + 4*ks];
      u16x4 o;
      o[0] = f2b(fmaxf(acc[f][0]+bi4.x, 0.f));
      o[1] = f2b(fmaxf(acc[f][1]+bi4.y, 0.f));
      o[2] = f2b(fmaxf(acc[f][2]+bi4.z, 0.f));
      o[3] = f2b(fmaxf(acc[f][3]+bi4.w, 0.f));
      *(u16x4*)&Hs[tl][f*16 + 4*ks] = o;
    }
  }
  __syncthreads();
  f32x4 acc2[8] = {};
  for (int kc = 0; kc < 256; kc += 32){
    bf16x8 a = *(const bf16x8*)&Hs[tl][kc + ks*8];
#pragma unroll
    for (int f = 0; f < 8; f++){
      bf16x8 w = *(const bf16x8*)(W2t + (size_t)(f*16 + r)*256 + kc + ks*8);
      acc2[f] = __builtin_amdgcn_mfma_f32_16x16x32_bf16(w, a, acc2[f], 0, 0, 0);
    }
  }
  float vv[8][4];
#pragma unroll
  for (int f = 0; f < 8; f++){
    float4 bi4 = *(const float4*)&b2[f*16 + 4*ks];
    u16x4 rr = *(const u16x4*)(A + trow*128 + f*16 + 4*ks);
    vv[f][0] = acc2[f][0] + bi4.x + b2f(rr[0]);
    vv[f][1] = acc2[f][1] + bi4.y + b2f(rr[1]);
    vv[f][2] = acc2[f][2] + bi4.z + b2f(rr[2]);
    vv[f][3] = acc2[f][3] + bi4.w + b2f(rr[3]);
  }
  float s = 0.f;
#pragma unroll
  for (int f = 0; f < 8; f++) s += vv[f][0]+vv[f][1]+vv[f][2]+vv[f][3];
  s += __shfl_xor(s, 16, 64); s += __shfl_xor(s, 32, 64);
  float mean = s * (1.f/128.f);
  float q = 0.f;
#pragma unroll
  for (int f = 0; f < 8; f++)
#pragma unroll
    for (int e = 0; e < 4; e++){ float d = vv[f][e]-mean; q += d*d; }
  q += __shfl_xor(q, 16, 64); q += __shfl_xor(q, 32, 64);
  float rstd = rsqrtf(q*(1.f/128.f) + 1e-5f);
#pragma unroll
  for (int f = 0; f < 8; f++){
    float4 g4 = *(const float4*)&g1[f*16 + 4*ks];
    float4 b4 = *(const float4*)&lb1[f*16 + 4*ks];
    u16x4 o;
    o[0] = f2b((vv[f][0]-mean)*rstd*g4.x + b4.x);
    o[1] = f2b((vv[f][1]-mean)*rstd*g4.y + b4.y);
    o[2] = f2b((vv[f][2]-mean)*rstd*g4.z + b4.z);
    o[3] = f2b((vv[f][3]-mean)*rstd*g4.w + b4.w);
    *(u16x4*)(Out + trow*128 + f*16 + 4*ks) = o;
  }
}

// ---------------- homography warp + bilinear sample (pixel-major ctx, bf16) ----------------
__global__ __launch_bounds__(128) void k_warp(const unsigned short* __restrict__ ctxref,
     const float* __restrict__ depth, const float* __restrict__ projs,
     unsigned short* __restrict__ ctxsrc){
  int bi = blockIdx.x; int n = bi / HWn; int p = bi - n*HWn;
  int y = p / WW, x = p - y*WW;
  const float* pr = &projs[n*12];
  float d = depth[n*HWn + p];
  float fx = (float)x, fy = (float)y;
  float px = (pr[0]*fx + pr[1]*fy + pr[2])*d + pr[9];
  float py = (pr[3]*fx + pr[4]*fy + pr[5])*d + pr[10];
  float pz = (pr[6]*fx + pr[7]*fy + pr[8])*d + pr[11];
  if (pz == 0.f) pz = 1e-9f;
  float xs = px/pz, ys = py/pz;
  float x0 = floorf(xs), y0 = floorf(ys);
  float wx = xs - x0, wy = ys - y0;
  int c = threadIdx.x;
  float acc = 0.f;
#pragma unroll
  for (int dy = 0; dy < 2; dy++){
    float cy = y0 + dy;
    float wyv = dy ? wy : 1.f - wy;
#pragma unroll
    for (int dx = 0; dx < 2; dx++){
      float cx = x0 + dx;
      float wxv = dx ? wx : 1.f - wx;
      bool valid = (cx >= 0.f) && (cx <= (float)(WW-1)) && (cy >= 0.f) && (cy <= (float)(HH-1));
      int xi = (int)fminf(fmaxf(cx, 0.f), (float)(WW-1));
      int yi = (int)fminf(fmaxf(cy, 0.f), (float)(HH-1));
      float v = b2f(ctxref[((size_t)(n*HWn) + yi*WW + xi)*128 + c]);
      acc += valid ? wxv*wyv*v : 0.f;
    }
  }
  ctxsrc[(size_t)bi*128 + c] = f2b(acc);
}

// ---------------- token build: transpose feature + PE + ctx, bf16 out ----------------
__global__ __launch_bounds__(256) void k_build(const float* __restrict__ feat,
      const unsigned short* __restrict__ ctx, unsigned short* __restrict__ out){
  __shared__ float tile[32][33];
  int tx = threadIdx.x, ty = threadIdx.y;
  int p0 = blockIdx.x*32, c0 = blockIdx.y*32, b = blockIdx.z;
  for (int i = ty; i < 32; i += 8)
    tile[i][tx] = feat[((size_t)(b*CD + c0 + i))*HWn + p0 + tx];
  __syncthreads();
  const float LOG1E4_32 = 0.28782313662425572f;  // ln(10000)/32
  for (int r = ty; r < 32; r += 8){
    int p = p0 + r, c = c0 + tx;
    int y = p / WW, x = p - y*WW;
    int i = c >> 2, j = c & 3;
    float dv = expf(-(float)i * LOG1E4_32);
    float pos = (j < 2) ? (float)(x + 1) : (float)(y + 1);
    float arg = pos * dv;
    float pe = (j & 1) ? cosf(arg) : sinf(arg);
    size_t o = ((size_t)(b*HWn) + p)*128 + c;
    out[o] = f2b(tile[tx][r] + pe + b2f(ctx[o]));
  }
}

// ---------------- final: bf16 streams -> f32 d_out ----------------
__global__ __launch_bounds__(256) void k_tofp32(const unsigned short* __restrict__ s,
                                                float* __restrict__ out){
  size_t i = ((size_t)blockIdx.x*256 + threadIdx.x)*4;
  u16x4 v = *(const u16x4*)(s + i);
  float4 o = { b2f(v[0]), b2f(v[1]), b2f(v[2]), b2f(v[3]) };
  *(float4*)(out + i) = o;
}

// ---------------- host ----------------
extern "C" void kernel_launch(void* const* d_in, const int* in_sizes, int n_in,
                              void* d_out, int out_size, void* d_ws, size_t ws_size,
                              hipStream_t stream) {
  const float* ref_feature = (const float*)d_in[0];
  const float* src_feature = (const float*)d_in[1];
  const float* ref_proj    = (const float*)d_in[2];
  const float* ref_i2w     = (const float*)d_in[4];
  const float* src_i2w     = (const float*)d_in[5];
  const float* depth       = (const float*)d_in[6];
  const float* attn_w      = (const float*)d_in[7];
  const float* attn_b      = (const float*)d_in[8];
  const float* ffn_w1      = (const float*)d_in[9];
  const float* ffn_b1      = (const float*)d_in[10];
  const float* ffn_w2      = (const float*)d_in[11];
  const float* ffn_b2      = (const float*)d_in[12];
  const float* ln_g        = (const float*)d_in[13];
  const float* ln_b        = (const float*)d_in[14];
  const float* rc_w        = (const float*)d_in[15];
  const float* rc_b        = (const float*)d_in[16];
  const float* bn2_g       = (const float*)d_in[17];
  const float* bn2_b       = (const float*)d_in[18];
  const float* cc_w        = (const float*)d_in[19];
  const float* cc_b        = (const float*)d_in[20];
  const float* bn1_g       = (const float*)d_in[21];
  const float* bn1_b       = (const float*)d_in[22];
  const float* fc1_w       = (const float*)d_in[23];
  const float* fc1_b       = (const float*)d_in[24];
  const float* fc2_w       = (const float*)d_in[25];
  const float* fc2_b       = (const float*)d_in[26];
  const float* ser_w       = (const float*)d_in[27];
  const float* ser_b       = (const float*)d_in[28];
  const float* see_w       = (const float*)d_in[29];
  const float* see_b       = (const float*)d_in[30];

  // small tail: KVPART(4*640*272) + KVFIN(4*2176) + PROJ + GATE (f32) + WT (bf16)
  const size_t small_f32 = (size_t)4*640*272 + 4*2176 + 32 + 256;
  const size_t small_bytes = small_f32*4 + (size_t)540672*2 + 4096;
  const size_t need_batch = (size_t)TOKN*2*8 + small_bytes;   // streams(2)+QKV(6) bf16
  bool BATCH = ws_size >= need_batch;
  const size_t CSEG = BATCH ? 2*TOKN : TOKN;

  char* p = (char*)d_ws;
  unsigned short* Rm = (unsigned short*)p; p += TOKN*2;
  unsigned short* Sm = (unsigned short*)p; p += TOKN*2;      // contiguous after Rm
  unsigned short* QB = (unsigned short*)p; p += CSEG*3*2;
  unsigned short* KB = QB + CSEG;
  unsigned short* VB = QB + 2*CSEG;
  float* KVPART = (float*)p; p += (size_t)(BATCH?4:2)*640*272*4;
  float* KVFIN  = (float*)p; p += (size_t)(BATCH?4:2)*2176*4;
  float* PROJ   = (float*)p; p += 32*4;
  float* GATE   = (float*)p; p += 256*4;
  unsigned short* WT = (unsigned short*)p;

  float* OUT = (float*)d_out;

  k_wconv<<<2112, 256, 0, stream>>>(attn_w, ffn_w1, ffn_w2, cc_w, WT);
  k_small<<<1, 256, 0, stream>>>(ref_proj, src_i2w, ref_i2w, bn1_g, bn1_b, fc1_w, fc1_b,
                                 fc2_w, fc2_b, ser_w, ser_b, see_w, see_b, PROJ, GATE);
  k_hmap<<<TT, 128, 0, stream>>>(depth, rc_w, rc_b, bn2_g, bn2_b, GATE, QB);
  k_bqkv<<<dim3(TT/64, 1), 256, 0, stream>>>(QB, WT + 524288, cc_b, KB, CSEG, 0);
  k_warp<<<TT, 128, 0, stream>>>(KB, depth, PROJ, VB);
  k_build<<<dim3(HWn/32, 4, BN), dim3(32, 8), 0, stream>>>(ref_feature, KB, Rm);
  k_build<<<dim3(HWn/32, 4, BN), dim3(32, 8), 0, stream>>>(src_feature, VB, Sm);

  auto encode = [&](unsigned short* x, const unsigned short* srcp, int l, int nTok){
    const unsigned short* ATW = WT + (size_t)l*65536;          // [4][128][128]
    const unsigned short* F1T = WT + 262144 + (size_t)l*32768;
    const unsigned short* F2T = WT + 393216 + (size_t)l*32768;
    const float* Bv = attn_b + (size_t)l*512;
    const float* g0 = ln_g + (size_t)l*256; const float* b0 = ln_b + (size_t)l*256;
    int nb = nTok/64, ng = nTok/HWn;
    if (x == srcp){
      k_bqkv<<<dim3(nb, 3), 256, 0, stream>>>(x, ATW, Bv, QB, CSEG, 0b011);
    } else {
      k_bqkv<<<dim3(nb, 1), 256, 0, stream>>>(x, ATW, Bv, QB, CSEG, 0b1);
      k_bqkv<<<dim3(nb, 2), 256, 0, stream>>>(srcp, ATW + 16384, Bv + 128, KB, CSEG, 0b01);
    }
    k_kvpart<<<ng*640, 256, 0, stream>>>(KB, VB, KVPART);
    k_kvreduce<<<ng*8, 320, 0, stream>>>(KVPART, KVFIN);
    k_fattn<<<nb, 256, 0, stream>>>(QB, x, KVFIN, ATW + 3*16384, Bv + 384, g0, b0, QB);
    k_fffn<<<nb, 256, 0, stream>>>(QB, F1T, ffn_b1 + (size_t)l*256, F2T,
                                   ffn_b2 + (size_t)l*128, g0 + 128, b0 + 128, x);
  };

  // layer 0: self
  if (BATCH) encode(Rm, Rm, 0, 2*TT);
  else { encode(Rm, Rm, 0, TT); encode(Sm, Sm, 0, TT); }
  // layer 1: cross (src uses updated ref)
  encode(Rm, Sm, 1, TT); encode(Sm, Rm, 1, TT);
  // layer 2: self
  if (BATCH) encode(Rm, Rm, 2, 2*TT);
  else { encode(Rm, Rm, 2, TT); encode(Sm, Sm, 2, TT); }
  // layer 3: cross
  encode(Rm, Sm, 3, TT); encode(Sm, Rm, 3, TT);

  k_tofp32<<<(unsigned)(2*TOKN/(256*4)), 256, 0, stream>>>(Rm, OUT);
}